// Round 12
// baseline (140.567 us; speedup 1.0000x reference)
//
#include <hip/hip_runtime.h>
#include <math.h>

#define D_DIM 4096
#define NWG 512                       // 2 WGs/CU x 256 CUs, all co-resident
#define WAVES_PER_WG 4
#define WSTRIDE (NWG * WAVES_PER_WG)  // 2048 waves; 16384/2048 = 8 rows/wave

typedef float v2f __attribute__((ext_vector_type(2)));

// ---- packed-f32 butterfly primitives (VOP3P) ----
__device__ __forceinline__ v2f bfly0(v2f a) {
    v2f d;
    asm("v_pk_add_f32 %0, %1, %2 op_sel:[0,1] op_sel_hi:[0,1] neg_hi:[0,1]"
        : "=v"(d) : "v"(a), "v"(a));
    return d;
}
__device__ __forceinline__ v2f pkadd(v2f a, v2f b) {
    v2f d; asm("v_pk_add_f32 %0, %1, %2" : "=v"(d) : "v"(a), "v"(b)); return d;
}
__device__ __forceinline__ v2f pksub(v2f a, v2f b) {
    v2f d; asm("v_pk_add_f32 %0, %1, %2 neg_lo:[0,1] neg_hi:[0,1]" : "=v"(d) : "v"(a), "v"(b)); return d;
}
__device__ __forceinline__ v2f pkmul(v2f a, v2f b) {
    v2f d; asm("v_pk_mul_f32 %0, %1, %2" : "=v"(d) : "v"(a), "v"(b)); return d;
}

// In-register FWHT over 6 bits: 64 values as 32 packed v2f (verified r2-r11).
__device__ __forceinline__ void radix64(v2f w[32]) {
#pragma unroll
    for (int p = 0; p < 32; ++p) w[p] = bfly0(w[p]);
#pragma unroll
    for (int s = 0; s < 5; ++s) {
        const int d = 1 << s;
#pragma unroll
        for (int p = 0; p < 32; ++p) {
            if (!(p & d)) {
                const v2f a = w[p];
                const v2f b = w[p + d];
                w[p]     = pkadd(a, b);
                w[p + d] = pksub(a, b);
            }
        }
    }
}

// u_perm[l*64 + m] = u[e]/64, e = (l>>2)*256 + m*4 + (l&3)  (B-layout;
// exactly the element phase-B lane l holds at register index m).
__global__ void compute_u_kernel(const float* __restrict__ g_mu,
                                 const float* __restrict__ g_rho,
                                 const float* __restrict__ eps,
                                 float* __restrict__ u_perm) {
    const int j = blockIdx.x * blockDim.x + threadIdx.x;
    if (j < D_DIM) {
        const int e = ((j >> 8) << 8) | ((j & 63) << 2) | ((j >> 6) & 3);
        const float r = g_rho[e];
        const float sp = (r > 20.0f) ? r : log1pf(expf(r));
        u_perm[j] = (g_mu[e] + sp * eps[e]) * 0.015625f;
    }
}

// raw x row -> 32 packed v2f (coalesced b128; e = 256k + 4l + q)
__device__ __forceinline__ void load_x(v2f (&w)[32], const float* __restrict__ xr, int l4) {
#pragma unroll
    for (int k = 0; k < 16; ++k) {
        const float4 xv = *reinterpret_cast<const float4*>(xr + (k << 8) + l4);
        w[2 * k]     = (v2f){xv.x, xv.y};
        w[2 * k + 1] = (v2f){xv.z, xv.w};
    }
}

// One full row, wave-local (verified round-3 dataflow; zero barriers):
//  consumes raw x in `w` (loaded one row ago -> compiler's vmcnt wait at the
//  s2-multiply retires ONLY those older loads, keeping `nxt` in flight),
//  prefetches row (row + WSTRIDE, clamped) into `nxt`.
__device__ __forceinline__ void process_row(int row, v2f (&w)[32], v2f (&nxt)[32],
                                            const float* __restrict__ x,
                                            const float* __restrict__ s1,
                                            const float* __restrict__ s2,
                                            const float* __restrict__ u_perm,
                                            float* __restrict__ out,
                                            int nrows, float* __restrict__ trb,
                                            int l, int l4, int L4) {
    // ---- 1. issue next-row prefetch first (no deps; pinned by sched_barrier) ----
    const int pr = min(row + WSTRIDE, nrows - 1);
    load_x(nxt, x + (size_t)pr * D_DIM, l4);
    __builtin_amdgcn_sched_barrier(0);

    // ---- 2. *s2 (first consume of w), FWHT bits {0,1,8..11} ----
#pragma unroll
    for (int k = 0; k < 16; ++k) {
        const float4 sv = *reinterpret_cast<const float4*>(s2 + (k << 8) + l4);
        w[2 * k]     = pkmul(w[2 * k],     (v2f){sv.x, sv.y});
        w[2 * k + 1] = pkmul(w[2 * k + 1], (v2f){sv.z, sv.w});
    }
    radix64(w);

    // ---- T1: scatter b32 writes (<=2-way banks), swizzled b128 reads ----
#pragma unroll
    for (int v = 0; v < 64; ++v)
        trb[(v << 6) + (l ^ ((v & 15) << 2))] = (v & 1) ? w[v >> 1].y : w[v >> 1].x;
#pragma unroll
    for (int k = 0; k < 16; ++k) {
        const float4 f = *reinterpret_cast<const float4*>(&trb[(l << 6) + ((k << 2) ^ L4)]);
        w[2 * k]     = (v2f){f.x, f.y};
        w[2 * k + 1] = (v2f){f.z, f.w};
    }

    // ---- phase B: FWHT bits {2..7}, *u (B-layout), FWHT bits {2..7} ----
    radix64(w);
#pragma unroll
    for (int k = 0; k < 16; ++k) {
        const float4 uv = *reinterpret_cast<const float4*>(u_perm + (l << 6) + (k << 2));
        w[2 * k]     = pkmul(w[2 * k],     (v2f){uv.x, uv.y});
        w[2 * k + 1] = pkmul(w[2 * k + 1], (v2f){uv.z, uv.w});
    }
    radix64(w);

    // ---- T2 ----
#pragma unroll
    for (int m = 0; m < 64; ++m)
        trb[(m << 6) + (l ^ ((m & 15) << 2))] = (m & 1) ? w[m >> 1].y : w[m >> 1].x;
#pragma unroll
    for (int k = 0; k < 16; ++k) {
        const float4 f = *reinterpret_cast<const float4*>(&trb[(l << 6) + ((k << 2) ^ L4)]);
        w[2 * k]     = (v2f){f.x, f.y};
        w[2 * k + 1] = (v2f){f.z, f.w};
    }

    // ---- phase A': FWHT bits {0,1,8..11}, *s1, coalesced b128 store ----
    radix64(w);
    float* __restrict__ orow = out + (size_t)row * D_DIM;
#pragma unroll
    for (int k = 0; k < 16; ++k) {
        const float4 sv = *reinterpret_cast<const float4*>(s1 + (k << 8) + l4);
        const v2f o0 = pkmul(w[2 * k],     (v2f){sv.x, sv.y});
        const v2f o1 = pkmul(w[2 * k + 1], (v2f){sv.z, sv.w});
        *reinterpret_cast<float4*>(orow + (k << 8) + l4) = make_float4(o0.x, o0.y, o1.x, o1.y);
    }
}

// Persistent kernel: 512 WGs x 4 waves; each wave owns a 16 KB trb slice and
// processes rows wid, wid+2048, ... independently (NO barriers; intra-wave
// DS ordering). Register ping-pong A/B gives depth-1 row prefetch with all
// waits compiler-managed (no glds, no manual vmcnt).
// LDS 64 KB/WG -> 2 WG/CU; VGPR ~180 (cap 256) -> 2 waves/SIMD = 8 waves/CU.
__global__ __launch_bounds__(256, 2) void whvi_kernel(const float* __restrict__ x,
                                                      const float* __restrict__ s1,
                                                      const float* __restrict__ s2,
                                                      const float* __restrict__ u_perm,
                                                      float* __restrict__ out,
                                                      int nrows) {
    __shared__ float trb_all[WAVES_PER_WG * D_DIM];  // 64 KB: 16 KB per wave
    const int l = threadIdx.x & 63;
    const int wv = threadIdx.x >> 6;
    float* __restrict__ trb = &trb_all[wv << 12];
    const int l4 = l << 2;
    const int L4 = (l & 15) << 2;

    const int wid = blockIdx.x * WAVES_PER_WG + wv;
    if (wid >= nrows) return;  // no barriers in kernel -> safe wave exit

    v2f A[32], B[32];

    // prologue: raw x of row wid into A
    load_x(A, x + (size_t)wid * D_DIM, l4);

    for (int r = wid; r < nrows; r += 2 * WSTRIDE) {
        process_row(r, A, B, x, s1, s2, u_perm, out, nrows, trb, l, l4, L4);
        if (r + WSTRIDE < nrows)
            process_row(r + WSTRIDE, B, A, x, s1, s2, u_perm, out, nrows, trb, l, l4, L4);
    }
}

extern "C" void kernel_launch(void* const* d_in, const int* in_sizes, int n_in,
                              void* d_out, int out_size, void* d_ws, size_t ws_size,
                              hipStream_t stream) {
    const float* x     = (const float*)d_in[0];
    const float* s1    = (const float*)d_in[1];
    const float* s2    = (const float*)d_in[2];
    const float* g_mu  = (const float*)d_in[3];
    const float* g_rho = (const float*)d_in[4];
    const float* eps   = (const float*)d_in[5];
    // d_in[6] = H : realized implicitly by the FWHT butterflies.

    float* u_perm = (float*)d_ws;
    float* out    = (float*)d_out;

    const int N = in_sizes[0] / D_DIM;

    compute_u_kernel<<<(D_DIM + 255) / 256, 256, 0, stream>>>(g_mu, g_rho, eps, u_perm);
    whvi_kernel<<<NWG, 256, 0, stream>>>(x, s1, s2, u_perm, out, N);
}